// Round 16
// baseline (917.049 us; speedup 1.0000x reference)
//
#include <hip/hip_runtime.h>
#include <stdint.h>

#define LSTEPS 64
#define BATCH 128
#define HID 256
#define NGATES 1024
#define NVOCAB 32000
#define GO_TOK 31999

typedef __bf16 bf16x8 __attribute__((ext_vector_type(8)));
typedef float f32x4 __attribute__((ext_vector_type(4)));
typedef unsigned short u16;
typedef u16 u16x8 __attribute__((ext_vector_type(8)));

#define GLDS16(gp, lp)                                                          \
  __builtin_amdgcn_global_load_lds(                                             \
      (const __attribute__((address_space(1))) void*)(gp),                      \
      (__attribute__((address_space(3))) void*)(lp), 16, 0, 0)

__device__ __forceinline__ u16 f2bf(float f) {
  union { float f; uint32_t u; } v; v.f = f;
  uint32_t u = v.u;
  return (u16)((u + 0x7FFFu + ((u >> 16) & 1u)) >> 16);
}
__device__ __forceinline__ float sigm(float x) {
  return 1.0f / (1.0f + __expf(-x));
}
__device__ __forceinline__ float tanh_f(float x) {
  return 2.0f / (1.0f + __expf(-2.0f * x)) - 1.0f;
}

// Pack W [J][256] f32 -> bf16 k-chunked [32][J][8]
__global__ void k_pack(const float* __restrict__ src, u16* __restrict__ dst, int J) {
  int j = blockIdx.x * 256 + threadIdx.x;
  int kb = blockIdx.y;
  const float* s = src + (size_t)j * HID + kb * 8;
  u16x8 o;
#pragma unroll
  for (int e = 0; e < 8; ++e) o[e] = f2bf(s[e]);
  *reinterpret_cast<u16x8*>(dst + ((size_t)kb * J + j) * 8) = o;
}

// Plain f32 -> bf16 row-major copy (projW)
__global__ void k_pack2(const float* __restrict__ src, u16* __restrict__ dst) {
  int i = blockIdx.x * 256 + threadIdx.x;
  const float* s = src + (size_t)i * 8;
  u16x8 o;
#pragma unroll
  for (int e = 0; e < 8; ++e) o[e] = f2bf(s[e]);
  *reinterpret_cast<u16x8*>(dst + (size_t)i * 8) = o;
}

__global__ void k_bsum(const float* __restrict__ a, const float* __restrict__ b, float* __restrict__ o) {
  int i = blockIdx.x * 256 + threadIdx.x;
  o[i] = a[i] + b[i];
}

// Gather embeddings -> X bf16 [8192][256]; row r = t*128+b: t==0 -> GO token
__global__ void k_gather(const int* __restrict__ outs, const float* __restrict__ embW, u16* __restrict__ X) {
  int idx = blockIdx.x * 256 + threadIdx.x;
  int r = idx >> 5, k8 = idx & 31;
  int t = r >> 7;
  int src = (t == 0) ? GO_TOK : outs[r];
  const float* p = embW + (size_t)src * HID + k8 * 8;
  u16x8 o;
#pragma unroll
  for (int e = 0; e < 8; ++e) o[e] = f2bf(p[e]);
  *reinterpret_cast<u16x8*>(X + (size_t)r * HID + k8 * 8) = o;
}

// 64x64-tile GEMM for G = X @ Wih^T + bsum (M=8192, N=1024)
__global__ __launch_bounds__(256, 2) void k_gemm(const u16* __restrict__ A, const u16* __restrict__ Bp,
                                                 const float* __restrict__ bias, float* __restrict__ C,
                                                 int N) {
  __shared__ __align__(16) u16 sA[64 * 256];
  __shared__ __align__(16) u16 sB[32 * 64 * 8];
  const int tid = threadIdx.x;
  const int m0 = blockIdx.y * 64;
  const int n0 = blockIdx.x * 64;
#pragma unroll
  for (int i = 0; i < 8; ++i) {
    int idx = tid + i * 256;
    int r = idx >> 5, k8 = idx & 31;
    *reinterpret_cast<uint4*>(&sA[(r * 32 + (k8 ^ (r & 7))) * 8]) =
        *reinterpret_cast<const uint4*>(&A[(size_t)(m0 + r) * HID + k8 * 8]);
  }
#pragma unroll
  for (int i = 0; i < 8; ++i) {
    int idx = tid + i * 256;
    int kb = idx >> 6, j = idx & 63;
    *reinterpret_cast<uint4*>(&sB[(kb * 64 + (j ^ ((kb & 3) << 2))) * 8]) =
        *reinterpret_cast<const uint4*>(&Bp[((size_t)kb * N + n0 + j) * 8]);
  }
  __syncthreads();
  const int wave = tid >> 6, lane = tid & 63;
  const int wm = wave >> 1, wn = wave & 1;
  const int lr = lane & 15, lk = lane >> 4;
  f32x4 acc[2][2] = {};
#pragma unroll
  for (int kk = 0; kk < 8; ++kk) {
    bf16x8 a[2], b[2];
    int k8 = kk * 4 + lk;
#pragma unroll
    for (int mt = 0; mt < 2; ++mt) {
      int r = wm * 32 + mt * 16 + lr;
      a[mt] = *reinterpret_cast<const bf16x8*>(&sA[(r * 32 + (k8 ^ (r & 7))) * 8]);
    }
#pragma unroll
    for (int nt = 0; nt < 2; ++nt) {
      int j = wn * 32 + nt * 16 + lr;
      b[nt] = *reinterpret_cast<const bf16x8*>(&sB[(k8 * 64 + (j ^ ((k8 & 3) << 2))) * 8]);
    }
#pragma unroll
    for (int mt = 0; mt < 2; ++mt)
#pragma unroll
      for (int nt = 0; nt < 2; ++nt)
        acc[mt][nt] = __builtin_amdgcn_mfma_f32_16x16x32_bf16(a[mt], b[nt], acc[mt][nt], 0, 0, 0);
  }
#pragma unroll
  for (int mt = 0; mt < 2; ++mt) {
#pragma unroll
    for (int nt = 0; nt < 2; ++nt) {
      int col = n0 + wn * 32 + nt * 16 + lr;
      float bs = bias[col];
#pragma unroll
      for (int i = 0; i < 4; ++i) {
        int row = m0 + wm * 32 + mt * 16 + lk * 4 + i;
        C[(size_t)row * N + col] = acc[mt][nt][i] + bs;
      }
    }
  }
}

// === fused recurrence + projection (XCD-partitioned plain-store writers) =====
// grid = 256 wgs x 512 thr, 112 KB LDS -> 1 wg/CU. Roles by (xcd=bid&7,
// slot=bid>>3), assuming round-robin wg->XCD (perf heuristic only):
//   xcd<2, slot<8   : 16 recurrence wgs (rid=slot*2+xcd; partner slot^4 = same
//                     XCD). Their XCD0/1 L2s see NO plain-store write traffic.
//   xcd>=2          : 192 PLAIN-store projection workers (write-combine through
//                     their own XCDs' L2 -> lifts the ~2.7 TB/s NT-path cap).
//   xcd<2, slot 8-11: 8 NT-store workers (NT bypasses L2 -> no recur thrash).
//   xcd<2, slot>=12 : 40 idle (exit).
// 200 uniform 160-col stripes; R10's throttled relaxed gate.
__global__ __launch_bounds__(512) void k_fused(const float* __restrict__ G,
                                               const u16* __restrict__ WhhTp,
                                               const float* __restrict__ h0,
                                               const float* __restrict__ c0,
                                               u16* __restrict__ h_all,
                                               u16* __restrict__ hx,
                                               unsigned* __restrict__ flags,
                                               unsigned* __restrict__ donecnt,
                                               const u16* __restrict__ projW,
                                               const float* __restrict__ projb,
                                               float* __restrict__ out) {
  __shared__ __align__(16) char smem[114688];
  const int tid = threadIdx.x;
  const int w = tid >> 6, lane = tid & 63;
  const int lr = lane & 15, lk = lane >> 4;
  const int xcd = blockIdx.x & 7, slot = blockIdx.x >> 3;

  if (xcd < 2 && slot < 8) {
    // ---------------- recurrence role (verbatim R6/R10, rid-mapped) --------
    u16* sh = (u16*)smem;                              // 8 KB
    float(*sg)[516] = (float(*)[516])(smem + 8192);    // 33 KB
    const int rid = slot * 2 + xcd;                    // 0..15
    const int bg = rid & 7, hh = rid >> 3, ph = hh ^ 1;

    bf16x8 whhA[4][4], whhB[4][4];
    int jg_[4];
#pragma unroll
    for (int nt = 0; nt < 4; ++nt) {
      int j = w * 64 + nt * 16 + lr;
      int jg = (j >> 7) * 256 + hh * 128 + (j & 127);
      jg_[nt] = jg;
#pragma unroll
      for (int kk = 0; kk < 4; ++kk) {
        int k8A = hh * 16 + kk * 4 + lk;
        int k8B = ph * 16 + kk * 4 + lk;
        whhA[nt][kk] = *reinterpret_cast<const bf16x8*>(&WhhTp[((size_t)k8A * NGATES + jg) * 8]);
        whhB[nt][kk] = *reinterpret_cast<const bf16x8*>(&WhhTp[((size_t)k8B * NGATES + jg) * 8]);
      }
    }
    const int b = tid >> 5, d4 = (tid & 31) * 4;
    f32x4 cc = *reinterpret_cast<const f32x4*>(&c0[(size_t)(bg * 16 + b) * HID + hh * 128 + d4]);
    {
      int r = tid >> 5, c8 = tid & 31;
      const float* p = h0 + (size_t)(bg * 16 + r) * HID + c8 * 8;
      u16x8 o;
#pragma unroll
      for (int e = 0; e < 8; ++e) o[e] = f2bf(p[e]);
      *reinterpret_cast<u16x8*>(&sh[(r * 32 + (c8 ^ (r & 7))) * 8]) = o;
    }
    __syncthreads();

    for (int t = 0; t < LSTEPS; ++t) {
      float gv[4][4];
#pragma unroll
      for (int nt = 0; nt < 4; ++nt)
#pragma unroll
        for (int i = 0; i < 4; ++i)
          gv[nt][i] = G[((size_t)t * BATCH + bg * 16 + lk * 4 + i) * NGATES + jg_[nt]];

      f32x4 acc[4] = {};
      {  // phase A: own-half K from LDS
        bf16x8 ah[4];
#pragma unroll
        for (int kk = 0; kk < 4; ++kk) {
          int c8 = hh * 16 + kk * 4 + lk;
          ah[kk] = *reinterpret_cast<const bf16x8*>(&sh[(lr * 32 + (c8 ^ (lr & 7))) * 8]);
        }
#pragma unroll
        for (int kk = 0; kk < 4; ++kk)
#pragma unroll
          for (int nt = 0; nt < 4; ++nt)
            acc[nt] = __builtin_amdgcn_mfma_f32_16x16x32_bf16(ah[kk], whhA[nt][kk], acc[nt], 0, 0, 0);
      }
      // phase B: partner-half K
      if (t == 0) {
        bf16x8 ah[4];
#pragma unroll
        for (int kk = 0; kk < 4; ++kk) {
          int c8 = ph * 16 + kk * 4 + lk;
          ah[kk] = *reinterpret_cast<const bf16x8*>(&sh[(lr * 32 + (c8 ^ (lr & 7))) * 8]);
        }
#pragma unroll
        for (int kk = 0; kk < 4; ++kk)
#pragma unroll
          for (int nt = 0; nt < 4; ++nt)
            acc[nt] = __builtin_amdgcn_mfma_f32_16x16x32_bf16(ah[kk], whhB[nt][kk], acc[nt], 0, 0, 0);
      } else {
        {
          const unsigned* f = &flags[(rid ^ 8) * 16];
          int it = 0;
          unsigned v;
          do {
            v = __hip_atomic_load(f, __ATOMIC_ACQUIRE, __HIP_MEMORY_SCOPE_AGENT);
          } while (v < (unsigned)t && ++it < (1 << 22));
        }
        bf16x8 ah[4];
#pragma unroll
        for (int kk = 0; kk < 4; ++kk)
          ah[kk] = *reinterpret_cast<const bf16x8*>(
              hx + (((t - 1) & 1) * BATCH + bg * 16 + lr) * HID + ph * 128 + (kk * 4 + lk) * 8);
#pragma unroll
        for (int kk = 0; kk < 4; ++kk)
#pragma unroll
          for (int nt = 0; nt < 4; ++nt)
            acc[nt] = __builtin_amdgcn_mfma_f32_16x16x32_bf16(ah[kk], whhB[nt][kk], acc[nt], 0, 0, 0);
      }
#pragma unroll
      for (int nt = 0; nt < 4; ++nt) {
        int j = w * 64 + nt * 16 + lr;
#pragma unroll
        for (int i = 0; i < 4; ++i) sg[lk * 4 + i][j] = acc[nt][i] + gv[nt][i];
      }
      __syncthreads();
      {
        f32x4 ig = *reinterpret_cast<const f32x4*>(&sg[b][d4]);
        f32x4 fg = *reinterpret_cast<const f32x4*>(&sg[b][128 + d4]);
        f32x4 gg = *reinterpret_cast<const f32x4*>(&sg[b][256 + d4]);
        f32x4 og = *reinterpret_cast<const f32x4*>(&sg[b][384 + d4]);
        u16 hb[4];
#pragma unroll
        for (int e = 0; e < 4; ++e) {
          float cn = sigm(fg[e]) * cc[e] + sigm(ig[e]) * tanh_f(gg[e]);
          cc[e] = cn;
          hb[e] = f2bf(sigm(og[e]) * tanh_f(cn));
        }
        uint2 hp;
        hp.x = (unsigned)hb[0] | ((unsigned)hb[1] << 16);
        hp.y = (unsigned)hb[2] | ((unsigned)hb[3] << 16);
        int c8 = hh * 16 + (d4 >> 3);
        *reinterpret_cast<uint2*>(&sh[(b * 32 + (c8 ^ (b & 7))) * 8 + (d4 & 7)]) = hp;
        *reinterpret_cast<uint2*>(&hx[((t & 1) * BATCH + bg * 16 + b) * HID + hh * 128 + d4]) = hp;
        unsigned long long hv = ((unsigned long long)hp.y << 32) | (unsigned long long)hp.x;
        __hip_atomic_store(
            (unsigned long long*)(h_all + ((size_t)t * BATCH + bg * 16 + b) * HID + hh * 128 + d4),
            hv, __ATOMIC_RELAXED, __HIP_MEMORY_SCOPE_AGENT);
      }
      __syncthreads();
      if (tid == 0) {
        __hip_atomic_store(&flags[rid * 16], (unsigned)(t + 1), __ATOMIC_RELEASE,
                           __HIP_MEMORY_SCOPE_AGENT);
        __hip_atomic_fetch_add(&donecnt[t * 16], 1u, __ATOMIC_RELEASE, __HIP_MEMORY_SCOPE_AGENT);
      }
    }
  } else if (xcd >= 2 || slot < 12) {
    // -------- stripe-stationary projection role (plain or NT stores) -------
    const int isNT = (xcd < 2);                     // 8 extras on XCD0/1 use NT
    const int p = isNT ? (192 + (slot - 8) * 2 + xcd) : ((xcd - 2) * 32 + slot);
    if (p >= 200) return;
    u16* sB = (u16*)smem;            // 160 rows x 32 k-chunks x 16B = 80 KB
    u16* sA = (u16*)(smem + 81920);  // [2][128 x 8 x 8] = 32 KB
    const int n0 = p * 160;
    const int wm = w >> 1, wn = w & 1;  // 4 x 2 wave grid: 32 rows x 80 cols

    // stage B panel once: 5120 chunks, 10 per thread
#pragma unroll
    for (int i = 0; i < 10; ++i) {
      int c = i * 512 + tid;
      int row = c >> 5, cl = c & 31, scc = cl ^ (row & 7);
      GLDS16(&projW[(size_t)(n0 + row) * HID + scc * 8], &sB[c * 8]);
    }
    float bs[5];
#pragma unroll
    for (int nt = 0; nt < 5; ++nt) bs[nt] = projb[n0 + wn * 80 + nt * 16 + lr];
    __syncthreads();

    for (int t = 0; t < LSTEPS; ++t) {
      const size_t m0 = (size_t)t * 128;
      if (tid == 0) {
        int it = 0;
        unsigned v;
        do {
          v = __hip_atomic_load(&donecnt[t * 16], __ATOMIC_RELAXED, __HIP_MEMORY_SCOPE_AGENT);
          if (v >= 16u) break;
          __builtin_amdgcn_s_sleep(16);
        } while (++it < (1 << 20));
        (void)__hip_atomic_load(&donecnt[t * 16], __ATOMIC_ACQUIRE, __HIP_MEMORY_SCOPE_AGENT);
      }
      __syncthreads();  // gate: h_all[t] fully written & device-visible

#define ASTAGE(bsel, ks)                                                        \
      {                                                                         \
        _Pragma("unroll") for (int i = 0; i < 2; ++i) {                         \
          int c = i * 512 + tid;                                                \
          int row = c >> 3, cl = c & 7, scc = cl ^ (row & 7);                   \
          GLDS16(&h_all[(m0 + row) * HID + (ks) * 64 + scc * 8],                \
                 &sA[(bsel) * 8192 + c * 8]);                                   \
        }                                                                       \
      }

      ASTAGE(0, 0)
      __syncthreads();
      f32x4 acc[2][5] = {};
      int buf = 0;
#pragma unroll
      for (int ks = 0; ks < 4; ++ks) {
        if (ks < 3) ASTAGE(buf ^ 1, ks + 1)
        const u16* sAc = &sA[buf * 8192];
#pragma unroll
        for (int kk = 0; kk < 2; ++kk) {
          int k8g = ks * 8 + kk * 4 + lk;
          bf16x8 a[2], bb[5];
#pragma unroll
          for (int mt = 0; mt < 2; ++mt) {
            int r = wm * 32 + mt * 16 + lr;
            a[mt] = *reinterpret_cast<const bf16x8*>(&sAc[(r * 8 + ((kk * 4 + lk) ^ (r & 7))) * 8]);
          }
#pragma unroll
          for (int nt = 0; nt < 5; ++nt) {
            int r = wn * 80 + nt * 16 + lr;
            bb[nt] = *reinterpret_cast<const bf16x8*>(&sB[(r * 32 + (k8g ^ (r & 7))) * 8]);
          }
#pragma unroll
          for (int mt = 0; mt < 2; ++mt)
#pragma unroll
            for (int nt = 0; nt < 5; ++nt)
              acc[mt][nt] =
                  __builtin_amdgcn_mfma_f32_16x16x32_bf16(a[mt], bb[nt], acc[mt][nt], 0, 0, 0);
        }
        __syncthreads();
        buf ^= 1;
      }
#undef ASTAGE

#pragma unroll
      for (int mt = 0; mt < 2; ++mt) {
#pragma unroll
        for (int i = 0; i < 4; ++i) {
          size_t row = m0 + wm * 32 + mt * 16 + lk * 4 + i;
          float* cp = &out[row * NVOCAB + n0 + wn * 80];
          if (isNT) {
#pragma unroll
            for (int nt = 0; nt < 5; ++nt)
              __builtin_nontemporal_store(acc[mt][nt][i] + bs[nt], &cp[nt * 16 + lr]);
          } else {
#pragma unroll
            for (int nt = 0; nt < 5; ++nt)
              cp[nt * 16 + lr] = acc[mt][nt][i] + bs[nt];  // plain: L2 write-combine
          }
        }
      }
    }
  }
  // else: idle wgs on XCD0/1 (slot >= 12) exit immediately
}

extern "C" void kernel_launch(void* const* d_in, const int* in_sizes, int n_in,
                              void* d_out, int out_size, void* d_ws, size_t ws_size,
                              hipStream_t stream) {
  const int* outs = (const int*)d_in[0];
  const float* h0 = (const float*)d_in[1];
  const float* c0 = (const float*)d_in[2];
  const float* embW = (const float*)d_in[4];
  const float* W_ih = (const float*)d_in[5];
  const float* W_hh = (const float*)d_in[6];
  const float* b_ih = (const float*)d_in[7];
  const float* b_hh = (const float*)d_in[8];
  const float* proj_W = (const float*)d_in[9];
  const float* proj_b = (const float*)d_in[10];
  float* out = (float*)d_out;

  char* ws = (char*)d_ws;
  u16* Xbf      = (u16*)(ws + 0);            //  4,194,304 B  [8192][256] bf16
  u16* WihTp    = (u16*)(ws + 4194304);      //    524,288 B  [32][1024][8]
  u16* WhhTp    = (u16*)(ws + 4718592);      //    524,288 B  [32][1024][8]
  u16* projWbf  = (u16*)(ws + 5242880);      // 16,384,000 B  [32000][256] bf16
  u16* h_all    = (u16*)(ws + 21626880);     //  4,194,304 B  [64][128][256] bf16
  u16* hx       = (u16*)(ws + 25821184);     //    131,072 B  [2][128][256] bf16
  float* bsum   = (float*)(ws + 25952256);   //      4,096 B
  unsigned* flags   = (unsigned*)(ws + 25956352);  //  1,024 B (16 x 16 u32)
  unsigned* donecnt = (unsigned*)(ws + 25957376);  //  4,096 B (64 x 16 u32)
  float* G      = (float*)(ws + 25991168);   // 33,554,432 B  [8192][1024] f32

  (void)hipMemsetAsync(flags, 0, 1024 + 4096, stream);  // flags + donecnt
  k_pack<<<dim3(4, 32), 256, 0, stream>>>(W_ih, WihTp, NGATES);
  k_pack<<<dim3(4, 32), 256, 0, stream>>>(W_hh, WhhTp, NGATES);
  k_pack2<<<dim3(4000), 256, 0, stream>>>(proj_W, projWbf);
  k_bsum<<<dim3(4), 256, 0, stream>>>(b_ih, b_hh, bsum);
  k_gather<<<dim3(1024), 256, 0, stream>>>(outs, embW, Xbf);
  // G = X @ Wih^T + (b_ih+b_hh): off the serial path
  k_gemm<<<dim3(16, 128), 256, 0, stream>>>(Xbf, WihTp, bsum, G, NGATES);
  // fused: XCD-partitioned — 16 recur (XCD0/1) + 192 plain-store + 8 NT workers
  k_fused<<<dim3(256), 512, 0, stream>>>(G, WhhTp, h0, c0, h_all, hx, flags, donecnt,
                                         projWbf, proj_b, out);
}

// Round 17
// 430.348 us; speedup vs baseline: 2.1309x; 2.1309x over previous
//
#include <hip/hip_runtime.h>
#include <stdint.h>

#define LSTEPS 64
#define BATCH 128
#define HID 256
#define NGATES 1024
#define NVOCAB 32000
#define GO_TOK 31999

typedef __bf16 bf16x8 __attribute__((ext_vector_type(8)));
typedef float f32x4 __attribute__((ext_vector_type(4)));
typedef unsigned short u16;
typedef u16 u16x8 __attribute__((ext_vector_type(8)));

#define GLDS16(gp, lp)                                                          \
  __builtin_amdgcn_global_load_lds(                                             \
      (const __attribute__((address_space(1))) void*)(gp),                      \
      (__attribute__((address_space(3))) void*)(lp), 16, 0, 0)

__device__ __forceinline__ u16 f2bf(float f) {
  union { float f; uint32_t u; } v; v.f = f;
  uint32_t u = v.u;
  return (u16)((u + 0x7FFFu + ((u >> 16) & 1u)) >> 16);
}
__device__ __forceinline__ float sigm(float x) {
  return 1.0f / (1.0f + __expf(-x));
}
__device__ __forceinline__ float tanh_f(float x) {
  return 2.0f / (1.0f + __expf(-2.0f * x)) - 1.0f;
}

// ===== merged prep: W packs + projW pack + bsum + gather + flag zeroing ======
// blocks [0,128): Wih pack | [128,256): Whh pack | [256,4256): projW pack |
// [4256,5280): embedding gather | [5280,5284): bsum | 5284: zero flags+donecnt
__global__ void k_prep(const float* __restrict__ Wih, const float* __restrict__ Whh,
                       const float* __restrict__ projW, const float* __restrict__ b_ih,
                       const float* __restrict__ b_hh, const int* __restrict__ outs,
                       const float* __restrict__ embW, u16* __restrict__ WihTp,
                       u16* __restrict__ WhhTp, u16* __restrict__ projWbf,
                       float* __restrict__ bsum, u16* __restrict__ Xbf,
                       unsigned* __restrict__ flagz) {
  const int b = blockIdx.x;
  const int tid = threadIdx.x;
  if (b < 256) {
    // W pack [1024][256] f32 -> [32][1024][8] bf16
    const float* src = (b < 128) ? Wih : Whh;
    u16* dst = (b < 128) ? WihTp : WhhTp;
    int idx = (b & 127) * 256 + tid;  // [0, 32768)
    int j = idx & 1023, kb = idx >> 10;
    const float* s = src + (size_t)j * HID + kb * 8;
    u16x8 o;
#pragma unroll
    for (int e = 0; e < 8; ++e) o[e] = f2bf(s[e]);
    *reinterpret_cast<u16x8*>(dst + ((size_t)kb * NGATES + j) * 8) = o;
  } else if (b < 4256) {
    // projW f32 -> bf16 row-major, 8 elems/thread
    size_t i = (size_t)(b - 256) * 256 + tid;
    const float* s = projW + i * 8;
    u16x8 o;
#pragma unroll
    for (int e = 0; e < 8; ++e) o[e] = f2bf(s[e]);
    *reinterpret_cast<u16x8*>(projWbf + i * 8) = o;
  } else if (b < 5280) {
    // gather embeddings -> X bf16 [8192][256]; t==0 -> GO token
    int idx = (b - 4256) * 256 + tid;  // [0, 262144)
    int r = idx >> 5, k8 = idx & 31;
    int t = r >> 7;
    int src = (t == 0) ? GO_TOK : outs[r];
    const float* p = embW + (size_t)src * HID + k8 * 8;
    u16x8 o;
#pragma unroll
    for (int e = 0; e < 8; ++e) o[e] = f2bf(p[e]);
    *reinterpret_cast<u16x8*>(Xbf + (size_t)r * HID + k8 * 8) = o;
  } else if (b < 5284) {
    int i = (b - 5280) * 256 + tid;
    bsum[i] = b_ih[i] + b_hh[i];
  } else {
    // zero flags (256 u32) + donecnt (1024 u32) = 1280 u32
    for (int k = tid; k < 1280; k += 256) flagz[k] = 0;
  }
}

// 64x64-tile GEMM for G = X @ Wih^T + bsum (M=8192, N=1024)
__global__ __launch_bounds__(256, 2) void k_gemm(const u16* __restrict__ A, const u16* __restrict__ Bp,
                                                 const float* __restrict__ bias, float* __restrict__ C,
                                                 int N) {
  __shared__ __align__(16) u16 sA[64 * 256];
  __shared__ __align__(16) u16 sB[32 * 64 * 8];
  const int tid = threadIdx.x;
  const int m0 = blockIdx.y * 64;
  const int n0 = blockIdx.x * 64;
#pragma unroll
  for (int i = 0; i < 8; ++i) {
    int idx = tid + i * 256;
    int r = idx >> 5, k8 = idx & 31;
    *reinterpret_cast<uint4*>(&sA[(r * 32 + (k8 ^ (r & 7))) * 8]) =
        *reinterpret_cast<const uint4*>(&A[(size_t)(m0 + r) * HID + k8 * 8]);
  }
#pragma unroll
  for (int i = 0; i < 8; ++i) {
    int idx = tid + i * 256;
    int kb = idx >> 6, j = idx & 63;
    *reinterpret_cast<uint4*>(&sB[(kb * 64 + (j ^ ((kb & 3) << 2))) * 8]) =
        *reinterpret_cast<const uint4*>(&Bp[((size_t)kb * N + n0 + j) * 8]);
  }
  __syncthreads();
  const int wave = tid >> 6, lane = tid & 63;
  const int wm = wave >> 1, wn = wave & 1;
  const int lr = lane & 15, lk = lane >> 4;
  f32x4 acc[2][2] = {};
#pragma unroll
  for (int kk = 0; kk < 8; ++kk) {
    bf16x8 a[2], b[2];
    int k8 = kk * 4 + lk;
#pragma unroll
    for (int mt = 0; mt < 2; ++mt) {
      int r = wm * 32 + mt * 16 + lr;
      a[mt] = *reinterpret_cast<const bf16x8*>(&sA[(r * 32 + (k8 ^ (r & 7))) * 8]);
    }
#pragma unroll
    for (int nt = 0; nt < 2; ++nt) {
      int j = wn * 32 + nt * 16 + lr;
      b[nt] = *reinterpret_cast<const bf16x8*>(&sB[(k8 * 64 + (j ^ ((k8 & 3) << 2))) * 8]);
    }
#pragma unroll
    for (int mt = 0; mt < 2; ++mt)
#pragma unroll
      for (int nt = 0; nt < 2; ++nt)
        acc[mt][nt] = __builtin_amdgcn_mfma_f32_16x16x32_bf16(a[mt], b[nt], acc[mt][nt], 0, 0, 0);
  }
#pragma unroll
  for (int mt = 0; mt < 2; ++mt) {
#pragma unroll
    for (int nt = 0; nt < 2; ++nt) {
      int col = n0 + wn * 32 + nt * 16 + lr;
      float bs = bias[col];
#pragma unroll
      for (int i = 0; i < 4; ++i) {
        int row = m0 + wm * 32 + mt * 16 + lk * 4 + i;
        C[(size_t)row * N + col] = acc[mt][nt][i] + bs;
      }
    }
  }
}

// ===================== fused recurrence + projection (R10 exact) =============
// grid = 141 wgs x 512 thr (16 recur + 125 proj), 160 KB LDS -> 1 wg/CU.
// wgs 0..15: LSTM recurrence (R6 known-good role).
// wgs 16..140: stripe-stationary projection, 256-col stripes, B-panel LDS-
//   resident, NT C-stores, throttled relaxed gate spin (R10's proven config).
__global__ __launch_bounds__(512) void k_fused(const float* __restrict__ G,
                                               const u16* __restrict__ WhhTp,
                                               const float* __restrict__ h0,
                                               const float* __restrict__ c0,
                                               u16* __restrict__ h_all,
                                               u16* __restrict__ hx,
                                               unsigned* __restrict__ flags,
                                               unsigned* __restrict__ donecnt,
                                               const u16* __restrict__ projW,
                                               const float* __restrict__ projb,
                                               float* __restrict__ out) {
  __shared__ __align__(16) char smem[163840];
  const int tid = threadIdx.x;
  const int w = tid >> 6, lane = tid & 63;
  const int lr = lane & 15, lk = lane >> 4;

  if (blockIdx.x < 16) {
    // ---------------- recurrence role (verbatim R6/R10) ----------------
    u16* sh = (u16*)smem;                              // 8 KB
    float(*sg)[516] = (float(*)[516])(smem + 8192);    // 33 KB
    const int bid = blockIdx.x;
    const int bg = bid & 7, hh = bid >> 3, ph = hh ^ 1;

    bf16x8 whhA[4][4], whhB[4][4];
    int jg_[4];
#pragma unroll
    for (int nt = 0; nt < 4; ++nt) {
      int j = w * 64 + nt * 16 + lr;
      int jg = (j >> 7) * 256 + hh * 128 + (j & 127);
      jg_[nt] = jg;
#pragma unroll
      for (int kk = 0; kk < 4; ++kk) {
        int k8A = hh * 16 + kk * 4 + lk;
        int k8B = ph * 16 + kk * 4 + lk;
        whhA[nt][kk] = *reinterpret_cast<const bf16x8*>(&WhhTp[((size_t)k8A * NGATES + jg) * 8]);
        whhB[nt][kk] = *reinterpret_cast<const bf16x8*>(&WhhTp[((size_t)k8B * NGATES + jg) * 8]);
      }
    }
    const int b = tid >> 5, d4 = (tid & 31) * 4;
    f32x4 cc = *reinterpret_cast<const f32x4*>(&c0[(size_t)(bg * 16 + b) * HID + hh * 128 + d4]);
    {
      int r = tid >> 5, c8 = tid & 31;
      const float* p = h0 + (size_t)(bg * 16 + r) * HID + c8 * 8;
      u16x8 o;
#pragma unroll
      for (int e = 0; e < 8; ++e) o[e] = f2bf(p[e]);
      *reinterpret_cast<u16x8*>(&sh[(r * 32 + (c8 ^ (r & 7))) * 8]) = o;
    }
    __syncthreads();

    for (int t = 0; t < LSTEPS; ++t) {
      float gv[4][4];
#pragma unroll
      for (int nt = 0; nt < 4; ++nt)
#pragma unroll
        for (int i = 0; i < 4; ++i)
          gv[nt][i] = G[((size_t)t * BATCH + bg * 16 + lk * 4 + i) * NGATES + jg_[nt]];

      f32x4 acc[4] = {};
      {  // phase A: own-half K from LDS
        bf16x8 ah[4];
#pragma unroll
        for (int kk = 0; kk < 4; ++kk) {
          int c8 = hh * 16 + kk * 4 + lk;
          ah[kk] = *reinterpret_cast<const bf16x8*>(&sh[(lr * 32 + (c8 ^ (lr & 7))) * 8]);
        }
#pragma unroll
        for (int kk = 0; kk < 4; ++kk)
#pragma unroll
          for (int nt = 0; nt < 4; ++nt)
            acc[nt] = __builtin_amdgcn_mfma_f32_16x16x32_bf16(ah[kk], whhA[nt][kk], acc[nt], 0, 0, 0);
      }
      // phase B: partner-half K
      if (t == 0) {
        bf16x8 ah[4];
#pragma unroll
        for (int kk = 0; kk < 4; ++kk) {
          int c8 = ph * 16 + kk * 4 + lk;
          ah[kk] = *reinterpret_cast<const bf16x8*>(&sh[(lr * 32 + (c8 ^ (lr & 7))) * 8]);
        }
#pragma unroll
        for (int kk = 0; kk < 4; ++kk)
#pragma unroll
          for (int nt = 0; nt < 4; ++nt)
            acc[nt] = __builtin_amdgcn_mfma_f32_16x16x32_bf16(ah[kk], whhB[nt][kk], acc[nt], 0, 0, 0);
      } else {
        {
          const unsigned* f = &flags[(bid ^ 8) * 16];
          int it = 0;
          unsigned v;
          do {
            v = __hip_atomic_load(f, __ATOMIC_ACQUIRE, __HIP_MEMORY_SCOPE_AGENT);
          } while (v < (unsigned)t && ++it < (1 << 22));
        }
        bf16x8 ah[4];
#pragma unroll
        for (int kk = 0; kk < 4; ++kk)
          ah[kk] = *reinterpret_cast<const bf16x8*>(
              hx + (((t - 1) & 1) * BATCH + bg * 16 + lr) * HID + ph * 128 + (kk * 4 + lk) * 8);
#pragma unroll
        for (int kk = 0; kk < 4; ++kk)
#pragma unroll
          for (int nt = 0; nt < 4; ++nt)
            acc[nt] = __builtin_amdgcn_mfma_f32_16x16x32_bf16(ah[kk], whhB[nt][kk], acc[nt], 0, 0, 0);
      }
#pragma unroll
      for (int nt = 0; nt < 4; ++nt) {
        int j = w * 64 + nt * 16 + lr;
#pragma unroll
        for (int i = 0; i < 4; ++i) sg[lk * 4 + i][j] = acc[nt][i] + gv[nt][i];
      }
      __syncthreads();
      {
        f32x4 ig = *reinterpret_cast<const f32x4*>(&sg[b][d4]);
        f32x4 fg = *reinterpret_cast<const f32x4*>(&sg[b][128 + d4]);
        f32x4 gg = *reinterpret_cast<const f32x4*>(&sg[b][256 + d4]);
        f32x4 og = *reinterpret_cast<const f32x4*>(&sg[b][384 + d4]);
        u16 hb[4];
#pragma unroll
        for (int e = 0; e < 4; ++e) {
          float cn = sigm(fg[e]) * cc[e] + sigm(ig[e]) * tanh_f(gg[e]);
          cc[e] = cn;
          hb[e] = f2bf(sigm(og[e]) * tanh_f(cn));
        }
        uint2 hp;
        hp.x = (unsigned)hb[0] | ((unsigned)hb[1] << 16);
        hp.y = (unsigned)hb[2] | ((unsigned)hb[3] << 16);
        int c8 = hh * 16 + (d4 >> 3);
        *reinterpret_cast<uint2*>(&sh[(b * 32 + (c8 ^ (b & 7))) * 8 + (d4 & 7)]) = hp;
        *reinterpret_cast<uint2*>(&hx[((t & 1) * BATCH + bg * 16 + b) * HID + hh * 128 + d4]) = hp;
        unsigned long long hv = ((unsigned long long)hp.y << 32) | (unsigned long long)hp.x;
        __hip_atomic_store(
            (unsigned long long*)(h_all + ((size_t)t * BATCH + bg * 16 + b) * HID + hh * 128 + d4),
            hv, __ATOMIC_RELAXED, __HIP_MEMORY_SCOPE_AGENT);
      }
      __syncthreads();
      if (tid == 0) {
        __hip_atomic_store(&flags[bid * 16], (unsigned)(t + 1), __ATOMIC_RELEASE,
                           __HIP_MEMORY_SCOPE_AGENT);
        __hip_atomic_fetch_add(&donecnt[t * 16], 1u, __ATOMIC_RELEASE, __HIP_MEMORY_SCOPE_AGENT);
      }
    }
  } else {
    // ---------------- stripe-stationary projection role ----------------
    u16* sB = (u16*)smem;             // 256 rows x 32 k-chunks x 8 = 128 KB
    u16* sA = (u16*)(smem + 131072);  // [2][128 x 8 x 8] = 32 KB
    const int p = blockIdx.x - 16;    // 0..124
    const int n0 = p * 256;
    const int wm = w >> 2, wn = w & 3;  // 2 x 4 wave grid over 128 x 256

    // stage B panel once: [row][cl^(row&7)] <- projW[n0+row][HID]
#pragma unroll
    for (int i = 0; i < 16; ++i) {
      int c = i * 512 + tid;
      int row = c >> 5, cl = c & 31, scc = cl ^ (row & 7);
      GLDS16(&projW[(size_t)(n0 + row) * HID + scc * 8], &sB[c * 8]);
    }
    float bs[4];
#pragma unroll
    for (int nt = 0; nt < 4; ++nt) bs[nt] = projb[n0 + wn * 64 + nt * 16 + lr];
    __syncthreads();

    for (int t = 0; t < LSTEPS; ++t) {
      const size_t m0 = (size_t)t * 128;
      if (tid == 0) {
        // throttled relaxed spin; one ACQUIRE load on success for ordering
        int it = 0;
        unsigned v;
        do {
          v = __hip_atomic_load(&donecnt[t * 16], __ATOMIC_RELAXED, __HIP_MEMORY_SCOPE_AGENT);
          if (v >= 16u) break;
          __builtin_amdgcn_s_sleep(8);
        } while (++it < (1 << 20));
        (void)__hip_atomic_load(&donecnt[t * 16], __ATOMIC_ACQUIRE, __HIP_MEMORY_SCOPE_AGENT);
      }
      __syncthreads();  // gate: h_all[t] fully written & device-visible

#define ASTAGE(bsel, ks)                                                        \
      {                                                                         \
        _Pragma("unroll") for (int i = 0; i < 2; ++i) {                         \
          int c = i * 512 + tid;                                                \
          int row = c >> 3, cl = c & 7, scc = cl ^ (row & 7);                   \
          GLDS16(&h_all[(m0 + row) * HID + (ks) * 64 + scc * 8],                \
                 &sA[(bsel) * 8192 + c * 8]);                                   \
        }                                                                       \
      }

      ASTAGE(0, 0)
      __syncthreads();
      f32x4 acc[4][4] = {};
      int buf = 0;
#pragma unroll
      for (int ks = 0; ks < 4; ++ks) {
        if (ks < 3) ASTAGE(buf ^ 1, ks + 1)
        const u16* sAc = &sA[buf * 8192];
#pragma unroll
        for (int kk = 0; kk < 2; ++kk) {
          bf16x8 a[4], bb[4];
#pragma unroll
          for (int mt = 0; mt < 4; ++mt) {
            int r = wm * 64 + mt * 16 + lr;
            a[mt] = *reinterpret_cast<const bf16x8*>(&sAc[(r * 8 + ((kk * 4 + lk) ^ (r & 7))) * 8]);
          }
#pragma unroll
          for (int nt = 0; nt < 4; ++nt) {
            int r = wn * 64 + nt * 16 + lr;
            int k8g = ks * 8 + kk * 4 + lk;
            bb[nt] = *reinterpret_cast<const bf16x8*>(&sB[(r * 32 + (k8g ^ (r & 7))) * 8]);
          }
#pragma unroll
          for (int mt = 0; mt < 4; ++mt)
#pragma unroll
            for (int nt = 0; nt < 4; ++nt)
              acc[mt][nt] =
                  __builtin_amdgcn_mfma_f32_16x16x32_bf16(a[mt], bb[nt], acc[mt][nt], 0, 0, 0);
        }
        __syncthreads();
        buf ^= 1;
      }
#undef ASTAGE

#pragma unroll
      for (int mt = 0; mt < 4; ++mt) {
#pragma unroll
        for (int i = 0; i < 4; ++i) {
          size_t row = m0 + wm * 64 + mt * 16 + lk * 4 + i;
          float* cp = &out[row * NVOCAB + n0 + wn * 64];
#pragma unroll
          for (int nt = 0; nt < 4; ++nt)
            __builtin_nontemporal_store(acc[mt][nt][i] + bs[nt], &cp[nt * 16 + lr]);
        }
      }
    }
  }
}

extern "C" void kernel_launch(void* const* d_in, const int* in_sizes, int n_in,
                              void* d_out, int out_size, void* d_ws, size_t ws_size,
                              hipStream_t stream) {
  const int* outs = (const int*)d_in[0];
  const float* h0 = (const float*)d_in[1];
  const float* c0 = (const float*)d_in[2];
  const float* embW = (const float*)d_in[4];
  const float* W_ih = (const float*)d_in[5];
  const float* W_hh = (const float*)d_in[6];
  const float* b_ih = (const float*)d_in[7];
  const float* b_hh = (const float*)d_in[8];
  const float* proj_W = (const float*)d_in[9];
  const float* proj_b = (const float*)d_in[10];
  float* out = (float*)d_out;

  char* ws = (char*)d_ws;
  u16* Xbf      = (u16*)(ws + 0);            //  4,194,304 B  [8192][256] bf16
  u16* WihTp    = (u16*)(ws + 4194304);      //    524,288 B  [32][1024][8]
  u16* WhhTp    = (u16*)(ws + 4718592);      //    524,288 B  [32][1024][8]
  u16* projWbf  = (u16*)(ws + 5242880);      // 16,384,000 B  [32000][256] bf16
  u16* h_all    = (u16*)(ws + 21626880);     //  4,194,304 B  [64][128][256] bf16
  u16* hx       = (u16*)(ws + 25821184);     //    131,072 B  [2][128][256] bf16
  float* bsum   = (float*)(ws + 25952256);   //      4,096 B
  unsigned* flags   = (unsigned*)(ws + 25956352);  // 1,024 B (16 x 16 u32)
  unsigned* donecnt = (unsigned*)(ws + 25957376);  // 4,096 B (64 x 16 u32)
  float* G      = (float*)(ws + 25961472);   // 33,554,432 B  [8192][1024] f32

  // one merged prep dispatch (replaces 5 kernels + memset): packs, bsum,
  // gather, and zeroes flags+donecnt (flags is the base; donecnt follows it)
  k_prep<<<dim3(5285), 256, 0, stream>>>(W_ih, W_hh, proj_W, b_ih, b_hh, outs, embW,
                                         WihTp, WhhTp, projWbf, bsum, Xbf, flags);
  // G = X @ Wih^T + (b_ih+b_hh): off the serial path
  k_gemm<<<dim3(16, 128), 256, 0, stream>>>(Xbf, WihTp, bsum, G, NGATES);
  // fused: 16 recurrence wgs + 125 stripe-stationary projection wgs (R10 exact)
  k_fused<<<dim3(141), 512, 0, stream>>>(G, WhhTp, h0, c0, h_all, hx, flags, donecnt,
                                         projWbf, proj_b, out);
}